// Round 1
// baseline (438.102 us; speedup 1.0000x reference)
//
#include <hip/hip_runtime.h>
#include <cstdint>
#include <cstddef>

// ---------------------------------------------------------------------------
// TransformerEncoderLayer  B=2 S=2048 D=1024 H=16 HD=64 FF=4096
// bf16 MFMA compute, fp32 accum/softmax/LN.  Workspace use: 80MB + 12KB.
// ---------------------------------------------------------------------------

typedef __bf16 bf16;
typedef __bf16 bf16x2 __attribute__((ext_vector_type(2)));
typedef __bf16 bf16x4v __attribute__((ext_vector_type(4)));
typedef __bf16 bf16x8 __attribute__((ext_vector_type(8)));
typedef float  f32x4  __attribute__((ext_vector_type(4)));

#define NB 2
#define NS 2048
#define ND 1024
#define NH 16
#define NHD 64
#define NFF 4096
#define NM (NB*NS)   // 4096 rows

// global_load_lds: LDS dest is wave-uniform base + lane*16 (guide m104).
typedef uint32_t __attribute__((address_space(1))) gu32_t;
typedef uint32_t __attribute__((address_space(3))) lu32_t;
__device__ __forceinline__ void async_copy16(void* lds, const void* g) {
  __builtin_amdgcn_global_load_lds((gu32_t*)g, (lu32_t*)lds, 16, 0, 0);
}

__device__ __forceinline__ float gelu_f(float x) {
  return 0.5f * x * (1.0f + erff(x * 0.70710678118654752f));
}

// ---------------- transpose + fp32->bf16 (W[K][N] -> Wt[N][K]) -------------
__global__ __launch_bounds__(256) void transpose_cvt(
    const float* __restrict__ W, bf16* __restrict__ Wt, int K, int N) {
  __shared__ float t[32][33];
  int tx = threadIdx.x, ty = threadIdx.y;
  long bx = blockIdx.x, by = blockIdx.y;
#pragma unroll
  for (int r = 0; r < 4; ++r)
    t[ty + r*8][tx] = W[(by*32 + ty + r*8) * (long)N + bx*32 + tx];
  __syncthreads();
#pragma unroll
  for (int r = 0; r < 4; ++r)
    Wt[(bx*32 + ty + r*8) * (long)K + by*32 + tx] = (bf16)t[tx][ty + r*8];
}

// ---------------- bias concat (bq|bk|bv) -----------------------------------
__global__ __launch_bounds__(256) void concat3(
    const float* __restrict__ a, const float* __restrict__ b,
    const float* __restrict__ c, float* __restrict__ o) {
  int i = blockIdx.x * 256 + threadIdx.x;  // 3072
  o[i] = (i < ND) ? a[i] : ((i < 2*ND) ? b[i - ND] : c[i - 2*ND]);
}

// ---------------- layernorm fp32 -> bf16 -----------------------------------
__global__ __launch_bounds__(256) void ln_kernel(
    const float* __restrict__ x, const float* __restrict__ w,
    const float* __restrict__ b, bf16* __restrict__ out) {
  long row = blockIdx.x;
  int t = threadIdx.x;
  float4 v = ((const float4*)(x + row*ND))[t];
  float s  = v.x + v.y + v.z + v.w;
  float sq = v.x*v.x + v.y*v.y + v.z*v.z + v.w*v.w;
#pragma unroll
  for (int m = 1; m <= 32; m <<= 1) { s += __shfl_xor(s, m); sq += __shfl_xor(sq, m); }
  __shared__ float ss[4], ssq[4];
  if ((t & 63) == 0) { ss[t>>6] = s; ssq[t>>6] = sq; }
  __syncthreads();
  s  = ss[0] + ss[1] + ss[2] + ss[3];
  sq = ssq[0] + ssq[1] + ssq[2] + ssq[3];
  float mu = s * (1.0f/ND);
  float rs = rsqrtf(sq * (1.0f/ND) - mu*mu + 1e-5f);
  float4 wv = ((const float4*)w)[t];
  float4 bv = ((const float4*)b)[t];
  bf16x4v o;
  o[0] = (bf16)((v.x-mu)*rs*wv.x + bv.x);
  o[1] = (bf16)((v.y-mu)*rs*wv.y + bv.y);
  o[2] = (bf16)((v.z-mu)*rs*wv.z + bv.z);
  o[3] = (bf16)((v.w-mu)*rs*wv.w + bv.w);
  *(bf16x4v*)(out + row*ND + t*4) = o;
}

// ---------------- RoPE in-place on q and k (layout B,S,H*HD) ---------------
__global__ __launch_bounds__(256) void rope_kernel(bf16* __restrict__ q,
                                                   bf16* __restrict__ k) {
  long tid = (long)blockIdx.x * 256 + threadIdx.x;  // B*S*H*16
  int i = (int)(tid & 15);
  int h = (int)((tid >> 4) & 15);
  long bs = tid >> 8;                 // b*S + s
  int s = (int)(bs & (NS - 1));
  float ang = (float)s * exp2f(-(float)i * (13.287712379549449f / 16.0f));
  float sn, cs;
  sincosf(ang, &sn, &cs);
  long base = bs * ND + h * NHD + 2*i;
  bf16x2* qp = (bf16x2*)(q + base);
  bf16x2 qv = *qp;
  float q0 = (float)qv[0], q1 = (float)qv[1];
  bf16x2 qo; qo[0] = (bf16)(q0*cs - q1*sn); qo[1] = (bf16)(q1*cs + q0*sn);
  *qp = qo;
  bf16x2* kp = (bf16x2*)(k + base);
  bf16x2 kv = *kp;
  float k0 = (float)kv[0], k1 = (float)kv[1];
  bf16x2 ko; ko[0] = (bf16)(k0*cs - k1*sn); ko[1] = (bf16)(k1*cs + k0*sn);
  *kp = ko;
}

// ---------------- GEMM: C[M,N] = A[M,K] * Bt[N,K]^T + bias (+epilogue) -----
// EPI: 1 = bf16 out + GELU, 2 = f32 out + residual, 3 = bf16 qkv-scatter
template<int EPI>
__global__ __launch_bounds__(256) void gemm_kernel(
    const bf16* __restrict__ A, const bf16* __restrict__ Bt,
    const float* __restrict__ bias, const float* __restrict__ res,
    void* __restrict__ Cout, int M, int N, int K) {
  __shared__ __align__(16) bf16 Alds[128*32];
  __shared__ __align__(16) bf16 Blds[128*32];
  const int tid = threadIdx.x, lane = tid & 63, w = tid >> 6;
  const int fr = lane & 15, k8 = (lane >> 4) * 8;
  const int wm = (w >> 1) * 64, wn = (w & 1) * 64;
  const long am0 = (long)blockIdx.y * 128;
  const long bn0 = (long)blockIdx.x * 128;
  const f32x4 fzero = {0.f, 0.f, 0.f, 0.f};

  f32x4 acc[4][4];
#pragma unroll
  for (int m = 0; m < 4; ++m)
#pragma unroll
    for (int n = 0; n < 4; ++n) acc[m][n] = fzero;

  for (int kt = 0; kt < K; kt += 32) {
    __syncthreads();
#pragma unroll
    for (int i = 0; i < 2; ++i) {
      int slot = i*256 + w*64 + lane;
      int r = slot >> 2, c = slot & 3;
      async_copy16(&Alds[(i*256 + w*64)*8], &A[(am0 + r)*K + kt + c*8]);
      async_copy16(&Blds[(i*256 + w*64)*8], &Bt[(bn0 + r)*K + kt + c*8]);
    }
    __syncthreads();
    bf16x8 af[4], bfv[4];
#pragma unroll
    for (int m = 0; m < 4; ++m) af[m]  = *(const bf16x8*)&Alds[(wm + m*16 + fr)*32 + k8];
#pragma unroll
    for (int n = 0; n < 4; ++n) bfv[n] = *(const bf16x8*)&Blds[(wn + n*16 + fr)*32 + k8];
#pragma unroll
    for (int m = 0; m < 4; ++m)
#pragma unroll
      for (int n = 0; n < 4; ++n)
        acc[m][n] = __builtin_amdgcn_mfma_f32_16x16x32_bf16(af[m], bfv[n], acc[m][n], 0, 0, 0);
  }

  const int rbase = (lane >> 4) * 4;
#pragma unroll
  for (int m = 0; m < 4; ++m) {
#pragma unroll
    for (int n = 0; n < 4; ++n) {
      long col = bn0 + wn + n*16 + fr;
      float bia = bias[col];
#pragma unroll
      for (int j = 0; j < 4; ++j) {
        long row = am0 + wm + m*16 + rbase + j;
        float val = acc[m][n][j] + bia;
        if (EPI == 1) {
          ((bf16*)Cout)[row * N + col] = (bf16)gelu_f(val);
        } else if (EPI == 2) {
          ((float*)Cout)[row * N + col] = val + res[row * N + col];
        } else {  // EPI == 3: qkv scatter, col -> (which, col&1023)
          long sub = col >> 10;
          ((bf16*)Cout)[sub * (long)(NM*(long)ND) + row * ND + (col & 1023)] = (bf16)val;
        }
      }
    }
  }
}

// ---------------- flash attention (64 q-rows/block, KV tile 64) ------------
__global__ __launch_bounds__(256) void attn_kernel(
    const bf16* __restrict__ q, const bf16* __restrict__ k,
    const bf16* __restrict__ v, const int* __restrict__ mask,
    bf16* __restrict__ out) {
  const int qt = blockIdx.x;                   // 0..31
  const int b = blockIdx.y >> 4, h = blockIdx.y & 15;
  const int tid = threadIdx.x, lane = tid & 63, w = tid >> 6;
  const int fr = lane & 15, kg = lane >> 4;
  const int k8 = kg * 8;

  __shared__ __align__(16) bf16 Klds[64*64];      // [key][d]  (XOR-swizzled)
  __shared__ __align__(16) bf16 Vt[64*64];        // [d][key]  (XOR-swizzled)
  __shared__ __align__(16) bf16 Plds[4][16*64];   // per-wave P [qrow][key]

  // Q fragments in registers (A operand), wave owns 16 q-rows
  const long qrow = (long)qt*64 + w*16 + fr;
  const bf16* qbase = q + ((long)b*NS + qrow)*ND + h*NHD;
  bf16x8 qf[2];
  qf[0] = *(const bf16x8*)(qbase + k8);
  qf[1] = *(const bf16x8*)(qbase + 32 + k8);

  const f32x4 fzero = {0.f, 0.f, 0.f, 0.f};
  f32x4 oacc[4];
#pragma unroll
  for (int n = 0; n < 4; ++n) oacc[n] = fzero;
  float mrow[4] = {-1e30f, -1e30f, -1e30f, -1e30f};
  float lrow[4] = {0.f, 0.f, 0.f, 0.f};
  const int* maskb = mask + (long)b*NS;

  for (int kt = 0; kt < NS/64; ++kt) {
    __syncthreads();
    // K tile -> LDS via global_load_lds, source pre-swizzled (chunk ^= row&7)
#pragma unroll
    for (int i = 0; i < 2; ++i) {
      int slot = i*256 + w*64 + lane;
      int row = slot >> 3, c = slot & 7;
      int csrc = c ^ (row & 7);
      async_copy16(&Klds[(i*256 + w*64)*8],
                   &k[((long)b*NS + (long)kt*64 + row)*ND + h*NHD + csrc*8]);
    }
    // V tile -> LDS transposed ([d][key]), swizzled writes, conflict-free
#pragma unroll
    for (int i = 0; i < 2; ++i) {
      int c = w + i*4;
      int key = lane;
      bf16x8 vv = *(const bf16x8*)&v[((long)b*NS + (long)kt*64 + key)*ND + h*NHD + c*8];
#pragma unroll
      for (int e = 0; e < 8; ++e) {
        int d = c*8 + e;
        int off = d*128 + ((((key>>3) ^ (d & 7)) << 4) | ((key & 7)*2));
        *(bf16*)((char*)Vt + off) = vv[e];
      }
    }
    __syncthreads();

    // S = Q K^T  (16x64 per wave)
    f32x4 sacc[4];
#pragma unroll
    for (int n = 0; n < 4; ++n) sacc[n] = fzero;
#pragma unroll
    for (int n = 0; n < 4; ++n) {
      int krow = n*16 + fr;
#pragma unroll
      for (int kk = 0; kk < 2; ++kk) {
        int off = krow*128 + ((((kk*4 + kg) ^ (krow & 7)) << 4));
        bf16x8 kf = *(const bf16x8*)((const char*)Klds + off);
        sacc[n] = __builtin_amdgcn_mfma_f32_16x16x32_bf16(qf[kk], kf, sacc[n], 0, 0, 0);
      }
    }

    // online softmax (rows = kg*4+j, cols = n*16+fr)
    float p[4][4], corr[4];
#pragma unroll
    for (int j = 0; j < 4; ++j) {
      float sv[4]; float mx = -1e30f;
#pragma unroll
      for (int n = 0; n < 4; ++n) {
        float val = sacc[n][j] * 0.125f;
        if (maskb[kt*64 + n*16 + fr] == 0) val = -1e9f;
        sv[n] = val; mx = fmaxf(mx, val);
      }
      mx = fmaxf(mx, __shfl_xor(mx, 1)); mx = fmaxf(mx, __shfl_xor(mx, 2));
      mx = fmaxf(mx, __shfl_xor(mx, 4)); mx = fmaxf(mx, __shfl_xor(mx, 8));
      float mnew = fmaxf(mrow[j], mx);
      float cr = expf(mrow[j] - mnew);
      corr[j] = cr; mrow[j] = mnew;
      float rs = 0.f;
#pragma unroll
      for (int n = 0; n < 4; ++n) { float pv = expf(sv[n] - mnew); p[n][j] = pv; rs += pv; }
      rs += __shfl_xor(rs, 1); rs += __shfl_xor(rs, 2);
      rs += __shfl_xor(rs, 4); rs += __shfl_xor(rs, 8);
      lrow[j] = lrow[j]*cr + rs;
    }
#pragma unroll
    for (int n = 0; n < 4; ++n)
#pragma unroll
      for (int j = 0; j < 4; ++j) oacc[n][j] *= corr[j];

    // P -> LDS (bf16, swizzled)
#pragma unroll
    for (int n = 0; n < 4; ++n) {
#pragma unroll
      for (int j = 0; j < 4; ++j) {
        int pr = kg*4 + j, col = n*16 + fr;
        int off = pr*128 + ((((col>>3) ^ (pr & 7)) << 4) | ((col & 7)*2));
        *(bf16*)((char*)Plds[w] + off) = (bf16)p[n][j];
      }
    }
    __syncthreads();

    // O += P V
#pragma unroll
    for (int kk = 0; kk < 2; ++kk) {
      int offp = fr*128 + (((kk*4 + kg) ^ (fr & 7)) << 4);
      bf16x8 pa = *(const bf16x8*)((const char*)Plds[w] + offp);
#pragma unroll
      for (int n = 0; n < 4; ++n) {
        int vrow = n*16 + fr;
        int offv = vrow*128 + (((kk*4 + kg) ^ (vrow & 7)) << 4);
        bf16x8 vb = *(const bf16x8*)((const char*)Vt + offv);
        oacc[n] = __builtin_amdgcn_mfma_f32_16x16x32_bf16(pa, vb, oacc[n], 0, 0, 0);
      }
    }
  }

  // epilogue: divide by l, write (B,S,H*HD) bf16
#pragma unroll
  for (int j = 0; j < 4; ++j) {
    float inv = 1.0f / lrow[j];
    long orow = (long)qt*64 + w*16 + kg*4 + j;
    bf16* ob = out + ((long)b*NS + orow)*ND + h*NHD;
#pragma unroll
    for (int n = 0; n < 4; ++n) ob[n*16 + fr] = (bf16)(oacc[n][j] * inv);
  }
}

// ---------------------------------------------------------------------------
extern "C" void kernel_launch(void* const* d_in, const int* in_sizes, int n_in,
                              void* d_out, int out_size, void* d_ws, size_t ws_size,
                              hipStream_t stream) {
  const float* x    = (const float*)d_in[0];
  const int*   mask = (const int*)d_in[1];
  const float* wq   = (const float*)d_in[2];
  const float* bq   = (const float*)d_in[3];
  const float* wk   = (const float*)d_in[4];
  const float* bk   = (const float*)d_in[5];
  const float* wv   = (const float*)d_in[6];
  const float* bv   = (const float*)d_in[7];
  const float* wo   = (const float*)d_in[8];
  const float* bo   = (const float*)d_in[9];
  const float* ln1w = (const float*)d_in[10];
  const float* ln1b = (const float*)d_in[11];
  const float* ln2w = (const float*)d_in[12];
  const float* ln2b = (const float*)d_in[13];
  const float* w1   = (const float*)d_in[14];
  const float* b1   = (const float*)d_in[15];
  const float* w2   = (const float*)d_in[16];
  const float* b2   = (const float*)d_in[17];
  float* out = (float*)d_out;

  char* ws = (char*)d_ws;
  const size_t MB = 1024ull * 1024ull;
  // weights (persist whole call)
  bf16* wqt = (bf16*)(ws + 0*MB);    // 2MB each, wq|wk|wv contiguous for fused QKV
  bf16* wkt = (bf16*)(ws + 2*MB);
  bf16* wvt = (bf16*)(ws + 4*MB);
  bf16* wot = (bf16*)(ws + 6*MB);
  bf16* w1t = (bf16*)(ws + 8*MB);    // 8MB
  bf16* w2t = (bf16*)(ws + 16*MB);   // 8MB
  // activations (aliased over time)
  bf16* h1   = (bf16*)(ws + 24*MB);  // ln1 out; later aliased by attn_out, then f1
  bf16* qb   = (bf16*)(ws + 32*MB);  // q|k|v contiguous (8MB each)
  bf16* kb   = (bf16*)(ws + 40*MB);
  bf16* vb   = (bf16*)(ws + 48*MB);
  bf16* attn = h1;                   // alias: h1 dead after QKV
  bf16* f1   = (bf16*)(ws + 24*MB);  // 32MB, alias h1/q/k/v (dead after out-proj)
  float* y1  = (float*)(ws + 56*MB); // 16MB
  bf16* h2   = (bf16*)(ws + 72*MB);  // 8MB
  float* bcat = (float*)(ws + 80*MB);// 12KB
  (void)in_sizes; (void)n_in; (void)out_size; (void)ws_size;

  dim3 tb(32, 8);
  transpose_cvt<<<dim3(32, 32),  tb, 0, stream>>>(wq, wqt, ND, ND);
  transpose_cvt<<<dim3(32, 32),  tb, 0, stream>>>(wk, wkt, ND, ND);
  transpose_cvt<<<dim3(32, 32),  tb, 0, stream>>>(wv, wvt, ND, ND);
  transpose_cvt<<<dim3(32, 32),  tb, 0, stream>>>(wo, wot, ND, ND);
  transpose_cvt<<<dim3(128, 32), tb, 0, stream>>>(w1, w1t, ND, NFF);
  transpose_cvt<<<dim3(32, 128), tb, 0, stream>>>(w2, w2t, NFF, ND);
  concat3<<<12, 256, 0, stream>>>(bq, bk, bv, bcat);

  ln_kernel<<<NM, 256, 0, stream>>>(x, ln1w, ln1b, h1);

  // fused QKV: A=h1 (4096x1024), Bt=wqt|wkt|wvt (3072x1024), scatter to q,k,v
  gemm_kernel<3><<<dim3(24, 32), 256, 0, stream>>>(h1, wqt, bcat, nullptr, qb,
                                                   NM, 3*ND, ND);
  rope_kernel<<<4096, 256, 0, stream>>>(qb, kb);
  attn_kernel<<<dim3(NS/64, NB*NH), 256, 0, stream>>>(qb, kb, vb, mask, attn);

  // out-proj + residual(x) -> y1 (fp32)
  gemm_kernel<2><<<dim3(8, 32), 256, 0, stream>>>(attn, wot, bo, x, y1,
                                                  NM, ND, ND);
  ln_kernel<<<NM, 256, 0, stream>>>(y1, ln2w, ln2b, h2);
  // FFN1 + GELU -> f1 (bf16)
  gemm_kernel<1><<<dim3(32, 32), 256, 0, stream>>>(h2, w1t, b1, nullptr, f1,
                                                   NM, NFF, ND);
  // FFN2 + residual(y1) -> out (fp32)
  gemm_kernel<2><<<dim3(8, 32), 256, 0, stream>>>(f1, w2t, b2, y1, out,
                                                  NM, ND, NFF);
}

// Round 2
// 352.650 us; speedup vs baseline: 1.2423x; 1.2423x over previous
//
#include <hip/hip_runtime.h>
#include <cstdint>
#include <cstddef>

// ---------------------------------------------------------------------------
// TransformerEncoderLayer  B=2 S=2048 D=1024 H=16 HD=64 FF=4096
// bf16 MFMA compute, fp32 accum/softmax/LN.
// ---------------------------------------------------------------------------

typedef __bf16 bf16;
typedef __bf16 bf16x2 __attribute__((ext_vector_type(2)));
typedef __bf16 bf16x4v __attribute__((ext_vector_type(4)));
typedef __bf16 bf16x8 __attribute__((ext_vector_type(8)));
typedef float  f32x4  __attribute__((ext_vector_type(4)));

#define NB 2
#define NS 2048
#define ND 1024
#define NH 16
#define NHD 64
#define NFF 4096
#define NM (NB*NS)   // 4096 rows
#define QKSCALE 0.18033688011112042f   // 0.125 * log2(e)

// global_load_lds: LDS dest is wave-uniform base + lane*16 (guide m104).
typedef uint32_t __attribute__((address_space(1))) gu32_t;
typedef uint32_t __attribute__((address_space(3))) lu32_t;
__device__ __forceinline__ void async_copy16(void* lds, const void* g) {
  __builtin_amdgcn_global_load_lds((gu32_t*)g, (lu32_t*)lds, 16, 0, 0);
}

__device__ __forceinline__ float gelu_f(float x) {
  return 0.5f * x * (1.0f + erff(x * 0.70710678118654752f));
}

// ---------------- transpose + fp32->bf16 (W[K][N] -> Wt[N][K]) -------------
__global__ __launch_bounds__(256) void transpose_cvt(
    const float* __restrict__ W, bf16* __restrict__ Wt, int K, int N) {
  __shared__ float t[32][33];
  int tx = threadIdx.x, ty = threadIdx.y;
  long bx = blockIdx.x, by = blockIdx.y;
#pragma unroll
  for (int r = 0; r < 4; ++r)
    t[ty + r*8][tx] = W[(by*32 + ty + r*8) * (long)N + bx*32 + tx];
  __syncthreads();
#pragma unroll
  for (int r = 0; r < 4; ++r)
    Wt[(bx*32 + ty + r*8) * (long)K + by*32 + tx] = (bf16)t[tx][ty + r*8];
}

// ---------------- bias concat (bq|bk|bv) -----------------------------------
__global__ __launch_bounds__(256) void concat3(
    const float* __restrict__ a, const float* __restrict__ b,
    const float* __restrict__ c, float* __restrict__ o) {
  int i = blockIdx.x * 256 + threadIdx.x;  // 3072
  o[i] = (i < ND) ? a[i] : ((i < 2*ND) ? b[i - ND] : c[i - 2*ND]);
}

// ---------------- mask -> float bias in exp2 domain ------------------------
__global__ __launch_bounds__(256) void maskbias_kernel(
    const int* __restrict__ mask, float* __restrict__ mb) {
  int i = blockIdx.x * 256 + threadIdx.x;  // B*S
  mb[i] = mask[i] ? 0.0f : -1.0e9f;
}

// ---------------- layernorm fp32 -> bf16 -----------------------------------
__global__ __launch_bounds__(256) void ln_kernel(
    const float* __restrict__ x, const float* __restrict__ w,
    const float* __restrict__ b, bf16* __restrict__ out) {
  long row = blockIdx.x;
  int t = threadIdx.x;
  float4 v = ((const float4*)(x + row*ND))[t];
  float s  = v.x + v.y + v.z + v.w;
  float sq = v.x*v.x + v.y*v.y + v.z*v.z + v.w*v.w;
#pragma unroll
  for (int m = 1; m <= 32; m <<= 1) { s += __shfl_xor(s, m); sq += __shfl_xor(sq, m); }
  __shared__ float ss[4], ssq[4];
  if ((t & 63) == 0) { ss[t>>6] = s; ssq[t>>6] = sq; }
  __syncthreads();
  s  = ss[0] + ss[1] + ss[2] + ss[3];
  sq = ssq[0] + ssq[1] + ssq[2] + ssq[3];
  float mu = s * (1.0f/ND);
  float rs = rsqrtf(sq * (1.0f/ND) - mu*mu + 1e-5f);
  float4 wv = ((const float4*)w)[t];
  float4 bv = ((const float4*)b)[t];
  bf16x4v o;
  o[0] = (bf16)((v.x-mu)*rs*wv.x + bv.x);
  o[1] = (bf16)((v.y-mu)*rs*wv.y + bv.y);
  o[2] = (bf16)((v.z-mu)*rs*wv.z + bv.z);
  o[3] = (bf16)((v.w-mu)*rs*wv.w + bv.w);
  *(bf16x4v*)(out + row*ND + t*4) = o;
}

// ---------------- RoPE in-place on q and k (layout B,S,H*HD) ---------------
// q is pre-scaled by QKSCALE in the QKV epilogue; rotation commutes w/ scale.
__global__ __launch_bounds__(256) void rope_kernel(bf16* __restrict__ q,
                                                   bf16* __restrict__ k) {
  long tid = (long)blockIdx.x * 256 + threadIdx.x;  // B*S*H*16
  int i = (int)(tid & 15);
  int h = (int)((tid >> 4) & 15);
  long bs = tid >> 8;                 // b*S + s
  int s = (int)(bs & (NS - 1));
  float ang = (float)s * exp2f(-(float)i * (13.287712379549449f / 16.0f));
  float sn, cs;
  sincosf(ang, &sn, &cs);
  long base = bs * ND + h * NHD + 2*i;
  bf16x2* qp = (bf16x2*)(q + base);
  bf16x2 qv = *qp;
  float q0 = (float)qv[0], q1 = (float)qv[1];
  bf16x2 qo; qo[0] = (bf16)(q0*cs - q1*sn); qo[1] = (bf16)(q1*cs + q0*sn);
  *qp = qo;
  bf16x2* kp = (bf16x2*)(k + base);
  bf16x2 kv = *kp;
  float k0 = (float)kv[0], k1 = (float)kv[1];
  bf16x2 ko; ko[0] = (bf16)(k0*cs - k1*sn); ko[1] = (bf16)(k1*cs + k0*sn);
  *kp = ko;
}

// ---------------- GEMM: C[M,N] = A[M,K] * Bt[N,K]^T + bias (+epilogue) -----
// EPI: 1 = bf16 out + GELU, 2 = f32 out + residual, 3 = bf16 qkv-scatter
template<int EPI>
__global__ __launch_bounds__(256) void gemm_kernel(
    const bf16* __restrict__ A, const bf16* __restrict__ Bt,
    const float* __restrict__ bias, const float* __restrict__ res,
    void* __restrict__ Cout, int M, int N, int K) {
  __shared__ __align__(16) bf16 Alds[128*32];
  __shared__ __align__(16) bf16 Blds[128*32];
  const int tid = threadIdx.x, lane = tid & 63, w = tid >> 6;
  const int fr = lane & 15, k8 = (lane >> 4) * 8;
  const int wm = (w >> 1) * 64, wn = (w & 1) * 64;
  const long am0 = (long)blockIdx.y * 128;
  const long bn0 = (long)blockIdx.x * 128;
  const f32x4 fzero = {0.f, 0.f, 0.f, 0.f};

  f32x4 acc[4][4];
#pragma unroll
  for (int m = 0; m < 4; ++m)
#pragma unroll
    for (int n = 0; n < 4; ++n) acc[m][n] = fzero;

  for (int kt = 0; kt < K; kt += 32) {
    __syncthreads();
#pragma unroll
    for (int i = 0; i < 2; ++i) {
      int slot = i*256 + w*64 + lane;
      int r = slot >> 2, c = slot & 3;
      async_copy16(&Alds[(i*256 + w*64)*8], &A[(am0 + r)*K + kt + c*8]);
      async_copy16(&Blds[(i*256 + w*64)*8], &Bt[(bn0 + r)*K + kt + c*8]);
    }
    __syncthreads();
    bf16x8 af[4], bfv[4];
#pragma unroll
    for (int m = 0; m < 4; ++m) af[m]  = *(const bf16x8*)&Alds[(wm + m*16 + fr)*32 + k8];
#pragma unroll
    for (int n = 0; n < 4; ++n) bfv[n] = *(const bf16x8*)&Blds[(wn + n*16 + fr)*32 + k8];
#pragma unroll
    for (int m = 0; m < 4; ++m)
#pragma unroll
      for (int n = 0; n < 4; ++n)
        acc[m][n] = __builtin_amdgcn_mfma_f32_16x16x32_bf16(af[m], bfv[n], acc[m][n], 0, 0, 0);
  }

  const int rbase = (lane >> 4) * 4;
#pragma unroll
  for (int m = 0; m < 4; ++m) {
#pragma unroll
    for (int n = 0; n < 4; ++n) {
      long col = bn0 + wn + n*16 + fr;
      float bia = bias[col];
#pragma unroll
      for (int j = 0; j < 4; ++j) {
        long row = am0 + wm + m*16 + rbase + j;
        float val = acc[m][n][j] + bia;
        if (EPI == 1) {
          ((bf16*)Cout)[row * N + col] = (bf16)gelu_f(val);
        } else if (EPI == 2) {
          ((float*)Cout)[row * N + col] = val + res[row * N + col];
        } else {  // EPI == 3: qkv scatter, col -> (which, col&1023); q prescaled
          long sub = col >> 10;
          float sv = (sub == 0) ? val * QKSCALE : val;
          ((bf16*)Cout)[sub * (long)(NM*(long)ND) + row * ND + (col & 1023)] = (bf16)sv;
        }
      }
    }
  }
}

// ---------------- flash attention v2 ---------------------------------------
// Swapped QK^T (S^T layout) + permuted key rows so P packs in-lane for PV.
// No-max softmax in exp2 domain (scores bounded), deferred sum reduce.
__global__ __launch_bounds__(256) void attn_kernel(
    const bf16* __restrict__ q, const bf16* __restrict__ k,
    const bf16* __restrict__ v, const float* __restrict__ mbias,
    bf16* __restrict__ out) {
  const int qt = blockIdx.x;                   // 0..31
  const int b = blockIdx.y >> 4, h = blockIdx.y & 15;
  const int tid = threadIdx.x, lane = tid & 63, w = tid >> 6;
  const int fr = lane & 15, kg = lane >> 4;
  const int k8 = kg * 8;
  const int frl = fr & 3, frh = fr >> 2;

  __shared__ __align__(16) bf16 Klds[64*64];      // [key][d], swz c^(r&7)^((r>>3&1)<<2)
  __shared__ __align__(16) bf16 Vt[64*64];        // [d][key], swz c^(d&7)

  // Q fragments (B operand: lane holds Q[q=fr][d = kg*8..+8])
  const long qrow = (long)qt*64 + w*16 + fr;
  const bf16* qbase = q + ((long)b*NS + qrow)*ND + h*NHD;
  bf16x8 qf[2];
  qf[0] = *(const bf16x8*)(qbase + k8);
  qf[1] = *(const bf16x8*)(qbase + 32 + k8);

  const f32x4 fzero = {0.f, 0.f, 0.f, 0.f};
  f32x4 oacc[4];
#pragma unroll
  for (int n = 0; n < 4; ++n) oacc[n] = fzero;
  float lsum = 0.f;
  const float* mbb = mbias + (long)b*NS;

  for (int kt = 0; kt < NS/64; ++kt) {
    __syncthreads();
    // K tile -> LDS via global_load_lds, source pre-swizzled
#pragma unroll
    for (int i = 0; i < 2; ++i) {
      int slot = i*256 + w*64 + lane;
      int row = slot >> 3, c = slot & 7;
      int csrc = c ^ (row & 7) ^ (((row >> 3) & 1) << 2);
      async_copy16(&Klds[(i*256 + w*64)*8],
                   &k[((long)b*NS + (long)kt*64 + row)*ND + h*NHD + csrc*8]);
    }
    // V tile -> LDS transposed ([d][key]), swizzled scalar writes
#pragma unroll
    for (int i = 0; i < 2; ++i) {
      int c = w + i*4;
      int key = lane;
      bf16x8 vv = *(const bf16x8*)&v[((long)b*NS + (long)kt*64 + key)*ND + h*NHD + c*8];
#pragma unroll
      for (int e = 0; e < 8; ++e) {
        int d = c*8 + e;
        int off = d*128 + ((((key>>3) ^ (d & 7)) << 4) | ((key & 7)*2));
        *(bf16*)((char*)Vt + off) = vv[e];
      }
    }
    __syncthreads();

    // S^T = K Q^T per wave: sacc[n][j] = score(key = kg*8+(n&1)*4+j+(n>>1)*32, q = fr)
    f32x4 sacc[4];
#pragma unroll
    for (int n = 0; n < 4; ++n) sacc[n] = fzero;
#pragma unroll
    for (int n = 0; n < 4; ++n) {
      int r = (frh << 3) + ((n & 1) << 2) + frl + ((n >> 1) << 5);
      int swz = (r & 7) ^ (((r >> 3) & 1) << 2);
#pragma unroll
      for (int kk = 0; kk < 2; ++kk) {
        int off = r*128 + ((((kk << 2) | kg) ^ swz) << 4);
        bf16x8 kf = *(const bf16x8*)((const char*)Klds + off);
        sacc[n] = __builtin_amdgcn_mfma_f32_16x16x32_bf16(kf, qf[kk], sacc[n], 0, 0, 0);
      }
    }

    // no-max softmax in exp2 domain; P stays in registers
    float p[4][4];
#pragma unroll
    for (int n = 0; n < 4; ++n) {
      float4 mb = *(const float4*)&mbb[kt*64 + kg*8 + ((n & 1) << 2) + ((n >> 1) << 5)];
      p[n][0] = exp2f(sacc[n][0] + mb.x);
      p[n][1] = exp2f(sacc[n][1] + mb.y);
      p[n][2] = exp2f(sacc[n][2] + mb.z);
      p[n][3] = exp2f(sacc[n][3] + mb.w);
    }
#pragma unroll
    for (int n = 0; n < 4; ++n)
      lsum += (p[n][0] + p[n][1]) + (p[n][2] + p[n][3]);

    // pack P as PV A-fragments (in-lane: keys kk*32 + kg*8 .. +7)
    bf16x8 paf[2];
#pragma unroll
    for (int n = 0; n < 4; ++n) {
#pragma unroll
      for (int j = 0; j < 4; ++j)
        paf[n >> 1][((n & 1) << 2) + j] = (bf16)p[n][j];
    }

    // O += P V   (B operand: Vt[d = n2*16+fr][keys kk*32+kg*8..+8])
#pragma unroll
    for (int kk = 0; kk < 2; ++kk) {
#pragma unroll
      for (int n2 = 0; n2 < 4; ++n2) {
        int vrow = n2*16 + fr;
        int voff = vrow*128 + ((((kk << 2) | kg) ^ (vrow & 7)) << 4);
        bf16x8 vbf = *(const bf16x8*)((const char*)Vt + voff);
        oacc[n2] = __builtin_amdgcn_mfma_f32_16x16x32_bf16(paf[kk], vbf, oacc[n2], 0, 0, 0);
      }
    }
  }

  // final: reduce l across kg lanes, then write O / l
  lsum += __shfl_xor(lsum, 16);
  lsum += __shfl_xor(lsum, 32);
#pragma unroll
  for (int j = 0; j < 4; ++j) {
    float lj = __shfl(lsum, kg*4 + j);   // lane (kg*4+j) holds q-row kg*4+j
    float inv = 1.0f / lj;
    long orow = (long)qt*64 + w*16 + kg*4 + j;
    bf16* ob = out + ((long)b*NS + orow)*ND + h*NHD;
#pragma unroll
    for (int n2 = 0; n2 < 4; ++n2) ob[n2*16 + fr] = (bf16)(oacc[n2][j] * inv);
  }
}

// ---------------------------------------------------------------------------
extern "C" void kernel_launch(void* const* d_in, const int* in_sizes, int n_in,
                              void* d_out, int out_size, void* d_ws, size_t ws_size,
                              hipStream_t stream) {
  const float* x    = (const float*)d_in[0];
  const int*   mask = (const int*)d_in[1];
  const float* wq   = (const float*)d_in[2];
  const float* bq   = (const float*)d_in[3];
  const float* wk   = (const float*)d_in[4];
  const float* bk   = (const float*)d_in[5];
  const float* wv   = (const float*)d_in[6];
  const float* bv   = (const float*)d_in[7];
  const float* wo   = (const float*)d_in[8];
  const float* bo   = (const float*)d_in[9];
  const float* ln1w = (const float*)d_in[10];
  const float* ln1b = (const float*)d_in[11];
  const float* ln2w = (const float*)d_in[12];
  const float* ln2b = (const float*)d_in[13];
  const float* w1   = (const float*)d_in[14];
  const float* b1   = (const float*)d_in[15];
  const float* w2   = (const float*)d_in[16];
  const float* b2   = (const float*)d_in[17];
  float* out = (float*)d_out;

  char* ws = (char*)d_ws;
  const size_t MB = 1024ull * 1024ull;
  // weights (persist whole call)
  bf16* wqt = (bf16*)(ws + 0*MB);    // 2MB each, wq|wk|wv contiguous for fused QKV
  bf16* wkt = (bf16*)(ws + 2*MB);
  bf16* wvt = (bf16*)(ws + 4*MB);
  bf16* wot = (bf16*)(ws + 6*MB);
  bf16* w1t = (bf16*)(ws + 8*MB);    // 8MB
  bf16* w2t = (bf16*)(ws + 16*MB);   // 8MB
  // activations (aliased over time)
  bf16* h1   = (bf16*)(ws + 24*MB);  // ln1 out; later aliased by attn_out, then f1
  bf16* qb   = (bf16*)(ws + 32*MB);  // q|k|v contiguous (8MB each)
  bf16* kb   = (bf16*)(ws + 40*MB);
  bf16* vb   = (bf16*)(ws + 48*MB);
  bf16* attn = h1;                   // alias: h1 dead after QKV
  bf16* f1   = (bf16*)(ws + 24*MB);  // 32MB, alias h1/q/k/v (dead after out-proj)
  float* y1  = (float*)(ws + 56*MB); // 16MB
  bf16* h2   = (bf16*)(ws + 72*MB);  // 8MB
  float* bcat = (float*)(ws + 80*MB);          // 12KB
  float* mbf  = (float*)(ws + 80*MB + 12*1024);// 16KB (B*S floats)
  (void)in_sizes; (void)n_in; (void)out_size; (void)ws_size;

  dim3 tb(32, 8);
  transpose_cvt<<<dim3(32, 32),  tb, 0, stream>>>(wq, wqt, ND, ND);
  transpose_cvt<<<dim3(32, 32),  tb, 0, stream>>>(wk, wkt, ND, ND);
  transpose_cvt<<<dim3(32, 32),  tb, 0, stream>>>(wv, wvt, ND, ND);
  transpose_cvt<<<dim3(32, 32),  tb, 0, stream>>>(wo, wot, ND, ND);
  transpose_cvt<<<dim3(128, 32), tb, 0, stream>>>(w1, w1t, ND, NFF);
  transpose_cvt<<<dim3(32, 128), tb, 0, stream>>>(w2, w2t, NFF, ND);
  concat3<<<12, 256, 0, stream>>>(bq, bk, bv, bcat);
  maskbias_kernel<<<16, 256, 0, stream>>>(mask, mbf);

  ln_kernel<<<NM, 256, 0, stream>>>(x, ln1w, ln1b, h1);

  // fused QKV: A=h1 (4096x1024), Bt=wqt|wkt|wvt (3072x1024), scatter to q,k,v
  gemm_kernel<3><<<dim3(24, 32), 256, 0, stream>>>(h1, wqt, bcat, nullptr, qb,
                                                   NM, 3*ND, ND);
  rope_kernel<<<4096, 256, 0, stream>>>(qb, kb);
  attn_kernel<<<dim3(NS/64, NB*NH), 256, 0, stream>>>(qb, kb, vb, mbf, attn);

  // out-proj + residual(x) -> y1 (fp32)
  gemm_kernel<2><<<dim3(8, 32), 256, 0, stream>>>(attn, wot, bo, x, y1,
                                                  NM, ND, ND);
  ln_kernel<<<NM, 256, 0, stream>>>(y1, ln2w, ln2b, h2);
  // FFN1 + GELU -> f1 (bf16)
  gemm_kernel<1><<<dim3(32, 32), 256, 0, stream>>>(h2, w1t, b1, nullptr, f1,
                                                   NM, NFF, ND);
  // FFN2 + residual(y1) -> out (fp32)
  gemm_kernel<2><<<dim3(8, 32), 256, 0, stream>>>(f1, w2t, b2, y1, out,
                                                  NM, ND, NFF);
}

// Round 3
// 337.994 us; speedup vs baseline: 1.2962x; 1.0434x over previous
//
#include <hip/hip_runtime.h>
#include <cstdint>
#include <cstddef>

// ---------------------------------------------------------------------------
// TransformerEncoderLayer  B=2 S=2048 D=1024 H=16 HD=64 FF=4096
// bf16 MFMA compute, fp32 accum/softmax/LN.
// R3: GEMM prefetch-dbuf (T3-min) + XCD swizzle; attn V via ds_read_b64_tr_b16.
// ---------------------------------------------------------------------------

typedef __bf16 bf16;
typedef __bf16 bf16x2 __attribute__((ext_vector_type(2)));
typedef __bf16 bf16x4v __attribute__((ext_vector_type(4)));
typedef __bf16 bf16x8 __attribute__((ext_vector_type(8)));
typedef float  f32x4  __attribute__((ext_vector_type(4)));

#define NB 2
#define NS 2048
#define ND 1024
#define NH 16
#define NHD 64
#define NFF 4096
#define NM (NB*NS)   // 4096 rows
#define QKSCALE 0.18033688011112042f   // 0.125 * log2(e)

// global_load_lds: LDS dest is wave-uniform base + lane*16 (guide m104).
typedef uint32_t __attribute__((address_space(1))) gu32_t;
typedef uint32_t __attribute__((address_space(3))) lu32_t;
__device__ __forceinline__ void async_copy16(void* lds, const void* g) {
  __builtin_amdgcn_global_load_lds((gu32_t*)g, (lu32_t*)lds, 16, 0, 0);
}

// hardware transpose read: lane passing addr A receives bf16 elems at
// (A&~127) + ((A>>3)&15)*2 + j*32  (column (A>>3)&15 of the 128B [4][16] tile)
__device__ __forceinline__ bf16x4v tr_read16(const void* p) {
  typedef const __attribute__((address_space(3))) unsigned char* lp;
  bf16x4v d;
  asm volatile("ds_read_b64_tr_b16 %0, %1" : "=v"(d) : "v"((lp)p));
  return d;
}

__device__ __forceinline__ float gelu_f(float x) {
  return 0.5f * x * (1.0f + erff(x * 0.70710678118654752f));
}

// ---------------- transpose + fp32->bf16 (W[K][N] -> Wt[N][K]) -------------
__global__ __launch_bounds__(256) void transpose_cvt(
    const float* __restrict__ W, bf16* __restrict__ Wt, int K, int N) {
  __shared__ float t[32][33];
  int tx = threadIdx.x, ty = threadIdx.y;
  long bx = blockIdx.x, by = blockIdx.y;
#pragma unroll
  for (int r = 0; r < 4; ++r)
    t[ty + r*8][tx] = W[(by*32 + ty + r*8) * (long)N + bx*32 + tx];
  __syncthreads();
#pragma unroll
  for (int r = 0; r < 4; ++r)
    Wt[(bx*32 + ty + r*8) * (long)K + by*32 + tx] = (bf16)t[tx][ty + r*8];
}

// ---------------- bias concat (bq|bk|bv) -----------------------------------
__global__ __launch_bounds__(256) void concat3(
    const float* __restrict__ a, const float* __restrict__ b,
    const float* __restrict__ c, float* __restrict__ o) {
  int i = blockIdx.x * 256 + threadIdx.x;  // 3072
  o[i] = (i < ND) ? a[i] : ((i < 2*ND) ? b[i - ND] : c[i - 2*ND]);
}

// ---------------- mask -> float bias in exp2 domain ------------------------
__global__ __launch_bounds__(256) void maskbias_kernel(
    const int* __restrict__ mask, float* __restrict__ mb) {
  int i = blockIdx.x * 256 + threadIdx.x;  // B*S
  mb[i] = mask[i] ? 0.0f : -1.0e9f;
}

// ---------------- layernorm fp32 -> bf16 -----------------------------------
__global__ __launch_bounds__(256) void ln_kernel(
    const float* __restrict__ x, const float* __restrict__ w,
    const float* __restrict__ b, bf16* __restrict__ out) {
  long row = blockIdx.x;
  int t = threadIdx.x;
  float4 v = ((const float4*)(x + row*ND))[t];
  float s  = v.x + v.y + v.z + v.w;
  float sq = v.x*v.x + v.y*v.y + v.z*v.z + v.w*v.w;
#pragma unroll
  for (int m = 1; m <= 32; m <<= 1) { s += __shfl_xor(s, m); sq += __shfl_xor(sq, m); }
  __shared__ float ss[4], ssq[4];
  if ((t & 63) == 0) { ss[t>>6] = s; ssq[t>>6] = sq; }
  __syncthreads();
  s  = ss[0] + ss[1] + ss[2] + ss[3];
  sq = ssq[0] + ssq[1] + ssq[2] + ssq[3];
  float mu = s * (1.0f/ND);
  float rs = rsqrtf(sq * (1.0f/ND) - mu*mu + 1e-5f);
  float4 wv = ((const float4*)w)[t];
  float4 bv = ((const float4*)b)[t];
  bf16x4v o;
  o[0] = (bf16)((v.x-mu)*rs*wv.x + bv.x);
  o[1] = (bf16)((v.y-mu)*rs*wv.y + bv.y);
  o[2] = (bf16)((v.z-mu)*rs*wv.z + bv.z);
  o[3] = (bf16)((v.w-mu)*rs*wv.w + bv.w);
  *(bf16x4v*)(out + row*ND + t*4) = o;
}

// ---------------- RoPE in-place on q and k (layout B,S,H*HD) ---------------
__global__ __launch_bounds__(256) void rope_kernel(bf16* __restrict__ q,
                                                   bf16* __restrict__ k) {
  long tid = (long)blockIdx.x * 256 + threadIdx.x;  // B*S*H*16
  int i = (int)(tid & 15);
  int h = (int)((tid >> 4) & 15);
  long bs = tid >> 8;                 // b*S + s
  int s = (int)(bs & (NS - 1));
  float ang = (float)s * exp2f(-(float)i * (13.287712379549449f / 16.0f));
  float sn, cs;
  sincosf(ang, &sn, &cs);
  long base = bs * ND + h * NHD + 2*i;
  bf16x2* qp = (bf16x2*)(q + base);
  bf16x2 qv = *qp;
  float q0 = (float)qv[0], q1 = (float)qv[1];
  bf16x2 qo; qo[0] = (bf16)(q0*cs - q1*sn); qo[1] = (bf16)(q1*cs + q0*sn);
  *qp = qo;
  bf16x2* kp = (bf16x2*)(k + base);
  bf16x2 kv = *kp;
  float k0 = (float)kv[0], k1 = (float)kv[1];
  bf16x2 ko; ko[0] = (bf16)(k0*cs - k1*sn); ko[1] = (bf16)(k1*cs + k0*sn);
  *kp = ko;
}

// ---------------- GEMM: C[M,N] = A[M,K] * Bt[N,K]^T + bias (+epilogue) -----
// T3-min prefetch double-buffer + XCD-bijective block swizzle.
// EPI: 1 = bf16 out + GELU, 2 = f32 out + residual, 3 = bf16 qkv-scatter
template<int EPI>
__global__ __launch_bounds__(256) void gemm_kernel(
    const bf16* __restrict__ A, const bf16* __restrict__ Bt,
    const float* __restrict__ bias, const float* __restrict__ res,
    void* __restrict__ Cout, int M, int N, int K) {
  __shared__ __align__(16) bf16 Alds[2][128*32];
  __shared__ __align__(16) bf16 Blds[2][128*32];
  const int tid = threadIdx.x, lane = tid & 63, w = tid >> 6;
  const int fr = lane & 15, k8 = (lane >> 4) * 8;
  const int wm = (w >> 1) * 64, wn = (w & 1) * 64;

  // XCD swizzle (bijective: all grids have nwg % 8 == 0)
  const int gx = gridDim.x;
  int lin = blockIdx.y * gx + blockIdx.x;
  int nwg = gx * gridDim.y;
  int swz = (lin & 7) * (nwg >> 3) + (lin >> 3);
  const long am0 = (long)(swz / gx) * 128;
  const long bn0 = (long)(swz % gx) * 128;

  const f32x4 fzero = {0.f, 0.f, 0.f, 0.f};
  f32x4 acc[4][4];
#pragma unroll
  for (int m = 0; m < 4; ++m)
#pragma unroll
    for (int n = 0; n < 4; ++n) acc[m][n] = fzero;

  auto stage = [&](int kt, int bufi) {
#pragma unroll
    for (int i = 0; i < 2; ++i) {
      int slot = i*256 + tid;
      int r = slot >> 2, c = slot & 3;
      async_copy16((char*)&Alds[bufi][0] + i*4096 + w*1024,
                   &A[(am0 + r)*K + kt + c*8]);
      async_copy16((char*)&Blds[bufi][0] + i*4096 + w*1024,
                   &Bt[(bn0 + r)*K + kt + c*8]);
    }
  };

  const int nk = K >> 5;
  stage(0, 0);
  asm volatile("s_waitcnt vmcnt(0)" ::: "memory");
  __builtin_amdgcn_s_barrier();
  __builtin_amdgcn_sched_barrier(0);

  for (int t = 0; t < nk; ++t) {
    const int cur = t & 1;
    if (t + 1 < nk) stage((t + 1) * 32, cur ^ 1);
    const bf16* Ab = &Alds[cur][0];
    const bf16* Bb = &Blds[cur][0];
    bf16x8 af[4], bfv[4];
#pragma unroll
    for (int m = 0; m < 4; ++m) af[m]  = *(const bf16x8*)&Ab[(wm + m*16 + fr)*32 + k8];
#pragma unroll
    for (int n = 0; n < 4; ++n) bfv[n] = *(const bf16x8*)&Bb[(wn + n*16 + fr)*32 + k8];
#pragma unroll
    for (int m = 0; m < 4; ++m)
#pragma unroll
      for (int n = 0; n < 4; ++n)
        acc[m][n] = __builtin_amdgcn_mfma_f32_16x16x32_bf16(af[m], bfv[n], acc[m][n], 0, 0, 0);
    asm volatile("s_waitcnt vmcnt(0)" ::: "memory");
    __builtin_amdgcn_s_barrier();
    __builtin_amdgcn_sched_barrier(0);
  }

  const int rbase = (lane >> 4) * 4;
#pragma unroll
  for (int m = 0; m < 4; ++m) {
#pragma unroll
    for (int n = 0; n < 4; ++n) {
      long col = bn0 + wn + n*16 + fr;
      float bia = bias[col];
#pragma unroll
      for (int j = 0; j < 4; ++j) {
        long row = am0 + wm + m*16 + rbase + j;
        float val = acc[m][n][j] + bia;
        if (EPI == 1) {
          ((bf16*)Cout)[row * N + col] = (bf16)gelu_f(val);
        } else if (EPI == 2) {
          ((float*)Cout)[row * N + col] = val + res[row * N + col];
        } else {  // EPI == 3: qkv scatter, col -> (which, col&1023); q prescaled
          long sub = col >> 10;
          float sv = (sub == 0) ? val * QKSCALE : val;
          ((bf16*)Cout)[sub * (long)(NM*(long)ND) + row * ND + (col & 1023)] = (bf16)sv;
        }
      }
    }
  }
}

// ---------------- flash attention v3 ---------------------------------------
// Swapped QK^T; in-lane P; no-max exp2 softmax; V staged subtiled [kb][db][4][16]
// via global_load_lds and consumed with ds_read_b64_tr_b16; prefetch dbuf.
__global__ __launch_bounds__(256) void attn_kernel(
    const bf16* __restrict__ q, const bf16* __restrict__ k,
    const bf16* __restrict__ v, const float* __restrict__ mbias,
    bf16* __restrict__ out) {
  // XCD swizzle: each XCD owns 4 consecutive (b,h) pairs (KV 2MB fits its L2)
  int lin = blockIdx.y * 32 + blockIdx.x;       // grid (32, 32)
  int swz = (lin & 7) * 128 + (lin >> 3);
  const int qt = swz & 31;
  const int b = swz >> 9, h = (swz >> 5) & 15;
  const int tid = threadIdx.x, lane = tid & 63, w = tid >> 6;
  const int fr = lane & 15, kg = lane >> 4;
  const int k8 = kg * 8;
  const int frl = fr & 3, frh = fr >> 2;

  __shared__ __align__(16) bf16 Klds[2][64*64];   // [key][d], XOR-swizzled
  __shared__ __align__(16) bf16 Vlds[2][64*64];   // subtiled [kb][db][4][16]

  // Q fragments (B operand: lane holds Q[q=fr][d = kg*8..+8])
  const long qrow = (long)qt*64 + w*16 + fr;
  const bf16* qbase = q + ((long)b*NS + qrow)*ND + h*NHD;
  bf16x8 qf[2];
  qf[0] = *(const bf16x8*)(qbase + k8);
  qf[1] = *(const bf16x8*)(qbase + 32 + k8);

  const bf16* kbase = k + (long)b*NS*ND + h*NHD;
  const bf16* vbase = v + (long)b*NS*ND + h*NHD;

  auto stageK = [&](int kt, int bufi) {
#pragma unroll
    for (int i = 0; i < 2; ++i) {
      int slot = i*256 + tid;
      int row = slot >> 3, c = slot & 7;
      int csrc = c ^ (row & 7) ^ (((row >> 3) & 1) << 2);
      async_copy16((char*)&Klds[bufi][0] + i*4096 + w*1024,
                   kbase + ((long)kt*64 + row)*ND + csrc*8);
    }
  };
  // V subtiled: elem e (i*2048+tid*8): sub=e>>6, k=(sub>>2)*4+((e&63)>>4),
  // d=(sub&3)*16+(e&15)  ->  k = i*32+(tid>>5)*4+((tid&7)>>1), d=((tid>>3)&3)*16+(tid&1)*8
  auto stageV = [&](int kt, int bufi) {
#pragma unroll
    for (int i = 0; i < 2; ++i) {
      int kr = i*32 + (tid >> 5)*4 + ((tid & 7) >> 1);
      int dc = ((tid >> 3) & 3)*16 + (tid & 1)*8;
      async_copy16((char*)&Vlds[bufi][0] + i*4096 + w*1024,
                   vbase + ((long)kt*64 + kr)*ND + dc);
    }
  };

  const f32x4 fzero = {0.f, 0.f, 0.f, 0.f};
  f32x4 oacc[4];
#pragma unroll
  for (int n = 0; n < 4; ++n) oacc[n] = fzero;
  float lsum = 0.f;
  const float* mbb = mbias + (long)b*NS;

  stageK(0, 0);
  stageV(0, 0);
  asm volatile("s_waitcnt vmcnt(0)" ::: "memory");
  __builtin_amdgcn_s_barrier();
  __builtin_amdgcn_sched_barrier(0);

  const int NT = NS / 64;
  for (int kt = 0; kt < NT; ++kt) {
    const int cur = kt & 1;
    if (kt + 1 < NT) { stageK(kt + 1, cur ^ 1); stageV(kt + 1, cur ^ 1); }
    const char* Kb = (const char*)&Klds[cur][0];
    const char* Vb = (const char*)&Vlds[cur][0];

    // S^T: sacc[n][j] = score(key = kg*8+(n&1)*4+j+(n>>1)*32, q = fr)
    f32x4 sacc[4];
#pragma unroll
    for (int n = 0; n < 4; ++n) sacc[n] = fzero;
#pragma unroll
    for (int n = 0; n < 4; ++n) {
      int r = (frh << 3) + ((n & 1) << 2) + frl + ((n >> 1) << 5);
      int swzr = (r & 7) ^ (((r >> 3) & 1) << 2);
#pragma unroll
      for (int kk = 0; kk < 2; ++kk) {
        bf16x8 kf = *(const bf16x8*)(Kb + r*128 + ((((kk << 2) | kg) ^ swzr) << 4));
        sacc[n] = __builtin_amdgcn_mfma_f32_16x16x32_bf16(kf, qf[kk], sacc[n], 0, 0, 0);
      }
    }

    // no-max softmax in exp2 domain; P stays in registers
    float p[4][4];
#pragma unroll
    for (int n = 0; n < 4; ++n) {
      float4 mb = *(const float4*)&mbb[kt*64 + kg*8 + ((n & 1) << 2) + ((n >> 1) << 5)];
      p[n][0] = exp2f(sacc[n][0] + mb.x);
      p[n][1] = exp2f(sacc[n][1] + mb.y);
      p[n][2] = exp2f(sacc[n][2] + mb.z);
      p[n][3] = exp2f(sacc[n][3] + mb.w);
    }
#pragma unroll
    for (int n = 0; n < 4; ++n)
      lsum += (p[n][0] + p[n][1]) + (p[n][2] + p[n][3]);

    // pack P as PV A-fragments (in-lane: keys kk*32 + kg*8 .. +7)
    bf16x8 paf[2];
#pragma unroll
    for (int n = 0; n < 4; ++n) {
#pragma unroll
      for (int j = 0; j < 4; ++j)
        paf[n >> 1][((n & 1) << 2) + j] = (bf16)p[n][j];
    }

    // O += P V : B-frag = V^T[k = kk*32+kg*8+e][d = n2*16+fr] via tr reads
    // subtile sub = (kk*8 + kg*2 + t)*4 + n2 ; lane addr = sub*128 + fr*8
#pragma unroll
    for (int kk = 0; kk < 2; ++kk) {
      bf16x4v t0[4], t1[4];
#pragma unroll
      for (int n2 = 0; n2 < 4; ++n2) {
        t0[n2] = tr_read16(Vb + (((kk*8 + 0)*4 + n2)*128 + kg*1024 + fr*8));
        t1[n2] = tr_read16(Vb + (((kk*8 + 1)*4 + n2)*128 + kg*1024 + fr*8));
      }
      asm volatile("s_waitcnt lgkmcnt(0)" ::: "memory");
      __builtin_amdgcn_sched_barrier(0);
#pragma unroll
      for (int n2 = 0; n2 < 4; ++n2) {
        bf16x8 vb8 = __builtin_shufflevector(t0[n2], t1[n2], 0, 1, 2, 3, 4, 5, 6, 7);
        oacc[n2] = __builtin_amdgcn_mfma_f32_16x16x32_bf16(paf[kk], vb8, oacc[n2], 0, 0, 0);
      }
    }

    asm volatile("s_waitcnt vmcnt(0)" ::: "memory");
    __builtin_amdgcn_s_barrier();
    __builtin_amdgcn_sched_barrier(0);
  }

  // final: reduce l across kg lanes, then write O / l
  lsum += __shfl_xor(lsum, 16);
  lsum += __shfl_xor(lsum, 32);
#pragma unroll
  for (int j = 0; j < 4; ++j) {
    float lj = __shfl(lsum, kg*4 + j);   // lane (kg*4+j) holds q-row kg*4+j
    float inv = 1.0f / lj;
    long orow = (long)qt*64 + w*16 + kg*4 + j;
    bf16* ob = out + ((long)b*NS + orow)*ND + h*NHD;
#pragma unroll
    for (int n2 = 0; n2 < 4; ++n2) ob[n2*16 + fr] = (bf16)(oacc[n2][j] * inv);
  }
}

// ---------------------------------------------------------------------------
extern "C" void kernel_launch(void* const* d_in, const int* in_sizes, int n_in,
                              void* d_out, int out_size, void* d_ws, size_t ws_size,
                              hipStream_t stream) {
  const float* x    = (const float*)d_in[0];
  const int*   mask = (const int*)d_in[1];
  const float* wq   = (const float*)d_in[2];
  const float* bq   = (const float*)d_in[3];
  const float* wk   = (const float*)d_in[4];
  const float* bk   = (const float*)d_in[5];
  const float* wv   = (const float*)d_in[6];
  const float* bv   = (const float*)d_in[7];
  const float* wo   = (const float*)d_in[8];
  const float* bo   = (const float*)d_in[9];
  const float* ln1w = (const float*)d_in[10];
  const float* ln1b = (const float*)d_in[11];
  const float* ln2w = (const float*)d_in[12];
  const float* ln2b = (const float*)d_in[13];
  const float* w1   = (const float*)d_in[14];
  const float* b1   = (const float*)d_in[15];
  const float* w2   = (const float*)d_in[16];
  const float* b2   = (const float*)d_in[17];
  float* out = (float*)d_out;

  char* ws = (char*)d_ws;
  const size_t MB = 1024ull * 1024ull;
  bf16* wqt = (bf16*)(ws + 0*MB);    // wq|wk|wv contiguous for fused QKV
  bf16* wkt = (bf16*)(ws + 2*MB);
  bf16* wvt = (bf16*)(ws + 4*MB);
  bf16* wot = (bf16*)(ws + 6*MB);
  bf16* w1t = (bf16*)(ws + 8*MB);    // 8MB
  bf16* w2t = (bf16*)(ws + 16*MB);   // 8MB
  bf16* h1   = (bf16*)(ws + 24*MB);
  bf16* qb   = (bf16*)(ws + 32*MB);  // q|k|v contiguous (8MB each)
  bf16* kb   = (bf16*)(ws + 40*MB);
  bf16* vb   = (bf16*)(ws + 48*MB);
  bf16* attn = h1;                   // alias: h1 dead after QKV
  bf16* f1   = (bf16*)(ws + 24*MB);  // alias h1/q/k/v (dead after out-proj)
  float* y1  = (float*)(ws + 56*MB); // 16MB
  bf16* h2   = (bf16*)(ws + 72*MB);  // 8MB
  float* bcat = (float*)(ws + 80*MB);          // 12KB
  float* mbf  = (float*)(ws + 80*MB + 12*1024);// 16KB (B*S floats)
  (void)in_sizes; (void)n_in; (void)out_size; (void)ws_size;

  dim3 tb(32, 8);
  transpose_cvt<<<dim3(32, 32),  tb, 0, stream>>>(wq, wqt, ND, ND);
  transpose_cvt<<<dim3(32, 32),  tb, 0, stream>>>(wk, wkt, ND, ND);
  transpose_cvt<<<dim3(32, 32),  tb, 0, stream>>>(wv, wvt, ND, ND);
  transpose_cvt<<<dim3(32, 32),  tb, 0, stream>>>(wo, wot, ND, ND);
  transpose_cvt<<<dim3(128, 32), tb, 0, stream>>>(w1, w1t, ND, NFF);
  transpose_cvt<<<dim3(32, 128), tb, 0, stream>>>(w2, w2t, NFF, ND);
  concat3<<<12, 256, 0, stream>>>(bq, bk, bv, bcat);
  maskbias_kernel<<<16, 256, 0, stream>>>(mask, mbf);

  ln_kernel<<<NM, 256, 0, stream>>>(x, ln1w, ln1b, h1);

  // fused QKV: A=h1 (4096x1024), Bt=wqt|wkt|wvt (3072x1024), scatter to q,k,v
  gemm_kernel<3><<<dim3(24, 32), 256, 0, stream>>>(h1, wqt, bcat, nullptr, qb,
                                                   NM, 3*ND, ND);
  rope_kernel<<<4096, 256, 0, stream>>>(qb, kb);
  attn_kernel<<<dim3(NS/64, NB*NH), 256, 0, stream>>>(qb, kb, vb, mbf, attn);

  // out-proj + residual(x) -> y1 (fp32)
  gemm_kernel<2><<<dim3(8, 32), 256, 0, stream>>>(attn, wot, bo, x, y1,
                                                  NM, ND, ND);
  ln_kernel<<<NM, 256, 0, stream>>>(y1, ln2w, ln2b, h2);
  // FFN1 + GELU -> f1 (bf16)
  gemm_kernel<1><<<dim3(32, 32), 256, 0, stream>>>(h2, w1t, b1, nullptr, f1,
                                                   NM, NFF, ND);
  // FFN2 + residual(y1) -> out (fp32)
  gemm_kernel<2><<<dim3(8, 32), 256, 0, stream>>>(f1, w2t, b2, y1, out,
                                                  NM, ND, NFF);
}

// Round 4
// 326.218 us; speedup vs baseline: 1.3430x; 1.0361x over previous
//
#include <hip/hip_runtime.h>
#include <cstdint>
#include <cstddef>

// ---------------------------------------------------------------------------
// TransformerEncoderLayer  B=2 S=2048 D=1024 H=16 HD=64 FF=4096
// bf16 MFMA compute, fp32 accum/softmax/LN.
// R4: 256^2 4-phase GEMM (8 waves, BK=32, setprio) for QKV/FFN1; batched
//     transposes; attn unchanged from R3.
// ---------------------------------------------------------------------------

typedef __bf16 bf16;
typedef __bf16 bf16x2 __attribute__((ext_vector_type(2)));
typedef __bf16 bf16x4v __attribute__((ext_vector_type(4)));
typedef __bf16 bf16x8 __attribute__((ext_vector_type(8)));
typedef float  f32x4  __attribute__((ext_vector_type(4)));

#define NB 2
#define NS 2048
#define ND 1024
#define NH 16
#define NHD 64
#define NFF 4096
#define NM (NB*NS)   // 4096 rows
#define QKSCALE 0.18033688011112042f   // 0.125 * log2(e)

typedef uint32_t __attribute__((address_space(1))) gu32_t;
typedef uint32_t __attribute__((address_space(3))) lu32_t;
__device__ __forceinline__ void async_copy16(void* lds, const void* g) {
  __builtin_amdgcn_global_load_lds((gu32_t*)g, (lu32_t*)lds, 16, 0, 0);
}

__device__ __forceinline__ bf16x4v tr_read16(const void* p) {
  typedef const __attribute__((address_space(3))) unsigned char* lp;
  bf16x4v d;
  asm volatile("ds_read_b64_tr_b16 %0, %1" : "=v"(d) : "v"((lp)p));
  return d;
}

__device__ __forceinline__ float gelu_f(float x) {
  return 0.5f * x * (1.0f + erff(x * 0.70710678118654752f));
}

// ---------------- batched transpose + cvt for all 6 weights ----------------
// flat block id: [0,4096) -> wq/wk/wv/wo (D x D), [4096,8192) -> w1 (1024x4096),
// [8192,12288) -> w2 (4096x1024)
__global__ __launch_bounds__(256) void transpose_all(
    const float* __restrict__ wq, const float* __restrict__ wk,
    const float* __restrict__ wv, const float* __restrict__ wo,
    const float* __restrict__ w1, const float* __restrict__ w2,
    bf16* __restrict__ wqt, bf16* __restrict__ wkt, bf16* __restrict__ wvt,
    bf16* __restrict__ wot, bf16* __restrict__ w1t, bf16* __restrict__ w2t) {
  __shared__ float t[32][33];
  int flat = blockIdx.x;
  const float* W; bf16* Wt; long bx, by; int K, N;
  if (flat < 4096) {
    int which = flat >> 10, r = flat & 1023;
    const float* Ws[4] = {wq, wk, wv, wo};
    bf16* Wts[4] = {wqt, wkt, wvt, wot};
    W = Ws[which]; Wt = Wts[which]; bx = r & 31; by = r >> 5; K = ND; N = ND;
  } else if (flat < 8192) {
    int r = flat - 4096;
    W = w1; Wt = w1t; bx = r & 127; by = r >> 7; K = ND; N = NFF;
  } else {
    int r = flat - 8192;
    W = w2; Wt = w2t; bx = r & 31; by = r >> 5; K = NFF; N = ND;
  }
  int tx = threadIdx.x, ty = threadIdx.y;
#pragma unroll
  for (int r = 0; r < 4; ++r)
    t[ty + r*8][tx] = W[(by*32 + ty + r*8) * (long)N + bx*32 + tx];
  __syncthreads();
#pragma unroll
  for (int r = 0; r < 4; ++r)
    Wt[(bx*32 + ty + r*8) * (long)K + by*32 + tx] = (bf16)t[tx][ty + r*8];
}

// ---------------- bias concat + mask bias (one launch) ---------------------
__global__ __launch_bounds__(256) void smallfuse_kernel(
    const float* __restrict__ a, const float* __restrict__ b,
    const float* __restrict__ c, float* __restrict__ o,
    const int* __restrict__ mask, float* __restrict__ mb) {
  int blk = blockIdx.x;
  int t = threadIdx.x;
  if (blk < 12) {
    int i = blk * 256 + t;  // 3072
    o[i] = (i < ND) ? a[i] : ((i < 2*ND) ? b[i - ND] : c[i - 2*ND]);
  } else {
    int i = (blk - 12) * 256 + t;  // 4096 = B*S
    mb[i] = mask[i] ? 0.0f : -1.0e9f;
  }
}

// ---------------- layernorm fp32 -> bf16 -----------------------------------
__global__ __launch_bounds__(256) void ln_kernel(
    const float* __restrict__ x, const float* __restrict__ w,
    const float* __restrict__ b, bf16* __restrict__ out) {
  long row = blockIdx.x;
  int t = threadIdx.x;
  float4 v = ((const float4*)(x + row*ND))[t];
  float s  = v.x + v.y + v.z + v.w;
  float sq = v.x*v.x + v.y*v.y + v.z*v.z + v.w*v.w;
#pragma unroll
  for (int m = 1; m <= 32; m <<= 1) { s += __shfl_xor(s, m); sq += __shfl_xor(sq, m); }
  __shared__ float ss[4], ssq[4];
  if ((t & 63) == 0) { ss[t>>6] = s; ssq[t>>6] = sq; }
  __syncthreads();
  s  = ss[0] + ss[1] + ss[2] + ss[3];
  sq = ssq[0] + ssq[1] + ssq[2] + ssq[3];
  float mu = s * (1.0f/ND);
  float rs = rsqrtf(sq * (1.0f/ND) - mu*mu + 1e-5f);
  float4 wv = ((const float4*)w)[t];
  float4 bv = ((const float4*)b)[t];
  bf16x4v o;
  o[0] = (bf16)((v.x-mu)*rs*wv.x + bv.x);
  o[1] = (bf16)((v.y-mu)*rs*wv.y + bv.y);
  o[2] = (bf16)((v.z-mu)*rs*wv.z + bv.z);
  o[3] = (bf16)((v.w-mu)*rs*wv.w + bv.w);
  *(bf16x4v*)(out + row*ND + t*4) = o;
}

// ---------------- RoPE in-place on q and k (layout B,S,H*HD) ---------------
__global__ __launch_bounds__(256) void rope_kernel(bf16* __restrict__ q,
                                                   bf16* __restrict__ k) {
  long tid = (long)blockIdx.x * 256 + threadIdx.x;  // B*S*H*16
  int i = (int)(tid & 15);
  int h = (int)((tid >> 4) & 15);
  long bs = tid >> 8;                 // b*S + s
  int s = (int)(bs & (NS - 1));
  float ang = (float)s * exp2f(-(float)i * (13.287712379549449f / 16.0f));
  float sn, cs;
  sincosf(ang, &sn, &cs);
  long base = bs * ND + h * NHD + 2*i;
  bf16x2* qp = (bf16x2*)(q + base);
  bf16x2 qv = *qp;
  float q0 = (float)qv[0], q1 = (float)qv[1];
  bf16x2 qo; qo[0] = (bf16)(q0*cs - q1*sn); qo[1] = (bf16)(q1*cs + q0*sn);
  *qp = qo;
  bf16x2* kp = (bf16x2*)(k + base);
  bf16x2 kv = *kp;
  float k0 = (float)kv[0], k1 = (float)kv[1];
  bf16x2 ko; ko[0] = (bf16)(k0*cs - k1*sn); ko[1] = (bf16)(k1*cs + k0*sn);
  *kp = ko;
}

// ---------------- 128^2 GEMM (2-phase prefetch dbuf) -----------------------
// EPI: 1 = bf16 out + GELU, 2 = f32 out + residual, 3 = bf16 qkv-scatter
template<int EPI>
__global__ __launch_bounds__(256) void gemm_kernel(
    const bf16* __restrict__ A, const bf16* __restrict__ Bt,
    const float* __restrict__ bias, const float* __restrict__ res,
    void* __restrict__ Cout, int M, int N, int K) {
  __shared__ __align__(16) bf16 Alds[2][128*32];
  __shared__ __align__(16) bf16 Blds[2][128*32];
  const int tid = threadIdx.x, lane = tid & 63, w = tid >> 6;
  const int fr = lane & 15, k8 = (lane >> 4) * 8;
  const int wm = (w >> 1) * 64, wn = (w & 1) * 64;

  const int gx = gridDim.x;
  int lin = blockIdx.y * gx + blockIdx.x;
  int nwg = gx * gridDim.y;
  int swz = (lin & 7) * (nwg >> 3) + (lin >> 3);
  const long am0 = (long)(swz / gx) * 128;
  const long bn0 = (long)(swz % gx) * 128;

  const f32x4 fzero = {0.f, 0.f, 0.f, 0.f};
  f32x4 acc[4][4];
#pragma unroll
  for (int m = 0; m < 4; ++m)
#pragma unroll
    for (int n = 0; n < 4; ++n) acc[m][n] = fzero;

  auto stage = [&](int kt, int bufi) {
#pragma unroll
    for (int i = 0; i < 2; ++i) {
      int slot = i*256 + tid;
      int r = slot >> 2, c = slot & 3;
      async_copy16((char*)&Alds[bufi][0] + i*4096 + w*1024,
                   &A[(am0 + r)*K + kt + c*8]);
      async_copy16((char*)&Blds[bufi][0] + i*4096 + w*1024,
                   &Bt[(bn0 + r)*K + kt + c*8]);
    }
  };

  const int nk = K >> 5;
  stage(0, 0);
  asm volatile("s_waitcnt vmcnt(0)" ::: "memory");
  __builtin_amdgcn_s_barrier();
  __builtin_amdgcn_sched_barrier(0);

  for (int t = 0; t < nk; ++t) {
    const int cur = t & 1;
    if (t + 1 < nk) stage((t + 1) * 32, cur ^ 1);
    const bf16* Ab = &Alds[cur][0];
    const bf16* Bb = &Blds[cur][0];
    bf16x8 af[4], bfv[4];
#pragma unroll
    for (int m = 0; m < 4; ++m) af[m]  = *(const bf16x8*)&Ab[(wm + m*16 + fr)*32 + k8];
#pragma unroll
    for (int n = 0; n < 4; ++n) bfv[n] = *(const bf16x8*)&Bb[(wn + n*16 + fr)*32 + k8];
#pragma unroll
    for (int m = 0; m < 4; ++m)
#pragma unroll
      for (int n = 0; n < 4; ++n)
        acc[m][n] = __builtin_amdgcn_mfma_f32_16x16x32_bf16(af[m], bfv[n], acc[m][n], 0, 0, 0);
    asm volatile("s_waitcnt vmcnt(0)" ::: "memory");
    __builtin_amdgcn_s_barrier();
    __builtin_amdgcn_sched_barrier(0);
  }

  const int rbase = (lane >> 4) * 4;
#pragma unroll
  for (int m = 0; m < 4; ++m) {
#pragma unroll
    for (int n = 0; n < 4; ++n) {
      long col = bn0 + wn + n*16 + fr;
      float bia = bias[col];
#pragma unroll
      for (int j = 0; j < 4; ++j) {
        long row = am0 + wm + m*16 + rbase + j;
        float val = acc[m][n][j] + bia;
        if (EPI == 1) {
          ((bf16*)Cout)[row * N + col] = (bf16)gelu_f(val);
        } else if (EPI == 2) {
          ((float*)Cout)[row * N + col] = val + res[row * N + col];
        } else {
          long sub = col >> 10;
          float sv = (sub == 0) ? val * QKSCALE : val;
          ((bf16*)Cout)[sub * (long)(NM*(long)ND) + row * ND + (col & 1023)] = (bf16)sv;
        }
      }
    }
  }
}

// ---------------- 256^2 4-phase GEMM (8 waves, BK=32, setprio) -------------
// Wave grid 2M x 4N, wave tile 128x64. LDS rows 64B (conflict-free pattern).
template<int EPI>
__global__ __launch_bounds__(512, 2) void gemm256_kernel(
    const bf16* __restrict__ A, const bf16* __restrict__ Bt,
    const float* __restrict__ bias,
    void* __restrict__ Cout, int M, int N, int K) {
  __shared__ __align__(16) bf16 Alds[2][256*32];
  __shared__ __align__(16) bf16 Blds[2][256*32];
  const int tid = threadIdx.x, lane = tid & 63, w = tid >> 6;
  const int fr = lane & 15, k8 = (lane >> 4) * 8;
  const int wr = w >> 2, wc = w & 3;   // 2M x 4N

  const int gx = gridDim.x;
  int lin = blockIdx.y * gx + blockIdx.x;
  int nwg = gx * gridDim.y;
  int swz = (lin & 7) * (nwg >> 3) + (lin >> 3);
  const long am0 = (long)(swz / gx) * 256;
  const long bn0 = (long)(swz % gx) * 256;

  const f32x4 fzero = {0.f, 0.f, 0.f, 0.f};
  f32x4 acc[8][4];
#pragma unroll
  for (int m = 0; m < 8; ++m)
#pragma unroll
    for (int n = 0; n < 4; ++n) acc[m][n] = fzero;

  // 4 loads/thread per K-tile: 2 A-chunks + 2 B-chunks (16KB each tile half)
  auto stage = [&](int kt, int bufi) {
#pragma unroll
    for (int i = 0; i < 2; ++i) {
      int chunk = i*512 + tid;
      int r = chunk >> 2, c = chunk & 3;
      async_copy16((char*)&Alds[bufi][0] + i*8192 + w*1024,
                   &A[(am0 + r)*K + kt + c*8]);
      async_copy16((char*)&Blds[bufi][0] + i*8192 + w*1024,
                   &Bt[(bn0 + r)*K + kt + c*8]);
    }
  };

  const int nk = K >> 5;
  stage(0, 0);
  asm volatile("s_waitcnt vmcnt(0)" ::: "memory");
  __builtin_amdgcn_s_barrier();
  __builtin_amdgcn_sched_barrier(0);

  for (int t = 0; t < nk; ++t) {
    const int cur = t & 1;
    if (t + 1 < nk) stage((t + 1) * 32, cur ^ 1);
    const bf16* Ab = &Alds[cur][0];
    const bf16* Bb = &Blds[cur][0];
    bf16x8 af[4], bfv[4];
    // ---- phase A: B-frags (kept for phase B) + A-frags m0..3, 16 MFMA ----
#pragma unroll
    for (int n = 0; n < 4; ++n) bfv[n] = *(const bf16x8*)&Bb[(wc*64 + n*16 + fr)*32 + k8];
#pragma unroll
    for (int m = 0; m < 4; ++m) af[m]  = *(const bf16x8*)&Ab[(wr*128 + m*16 + fr)*32 + k8];
    asm volatile("s_waitcnt lgkmcnt(0)" ::: "memory");
    __builtin_amdgcn_sched_barrier(0);
    __builtin_amdgcn_s_setprio(1);
#pragma unroll
    for (int m = 0; m < 4; ++m)
#pragma unroll
      for (int n = 0; n < 4; ++n)
        acc[m][n] = __builtin_amdgcn_mfma_f32_16x16x32_bf16(af[m], bfv[n], acc[m][n], 0, 0, 0);
    __builtin_amdgcn_s_setprio(0);
    __builtin_amdgcn_s_barrier();
    // ---- phase B: A-frags m4..7, 16 MFMA ----
#pragma unroll
    for (int m = 0; m < 4; ++m) af[m] = *(const bf16x8*)&Ab[(wr*128 + (m+4)*16 + fr)*32 + k8];
    asm volatile("s_waitcnt lgkmcnt(0)" ::: "memory");
    __builtin_amdgcn_sched_barrier(0);
    __builtin_amdgcn_s_setprio(1);
#pragma unroll
    for (int m = 0; m < 4; ++m)
#pragma unroll
      for (int n = 0; n < 4; ++n)
        acc[m+4][n] = __builtin_amdgcn_mfma_f32_16x16x32_bf16(af[m], bfv[n], acc[m+4][n], 0, 0, 0);
    __builtin_amdgcn_s_setprio(0);
    asm volatile("s_waitcnt vmcnt(0)" ::: "memory");
    __builtin_amdgcn_s_barrier();
    __builtin_amdgcn_sched_barrier(0);
  }

  const int rbase = (lane >> 4) * 4;
#pragma unroll
  for (int m = 0; m < 8; ++m) {
#pragma unroll
    for (int n = 0; n < 4; ++n) {
      long col = bn0 + wc*64 + n*16 + fr;
      float bia = bias[col];
#pragma unroll
      for (int j = 0; j < 4; ++j) {
        long row = am0 + wr*128 + m*16 + rbase + j;
        float val = acc[m][n][j] + bia;
        if (EPI == 1) {
          ((bf16*)Cout)[row * N + col] = (bf16)gelu_f(val);
        } else {
          long sub = col >> 10;
          float sv = (sub == 0) ? val * QKSCALE : val;
          ((bf16*)Cout)[sub * (long)(NM*(long)ND) + row * ND + (col & 1023)] = (bf16)sv;
        }
      }
    }
  }
}

// ---------------- flash attention (unchanged from R3) ----------------------
__global__ __launch_bounds__(256) void attn_kernel(
    const bf16* __restrict__ q, const bf16* __restrict__ k,
    const bf16* __restrict__ v, const float* __restrict__ mbias,
    bf16* __restrict__ out) {
  int lin = blockIdx.y * 32 + blockIdx.x;       // grid (32, 32)
  int swz = (lin & 7) * 128 + (lin >> 3);
  const int qt = swz & 31;
  const int b = swz >> 9, h = (swz >> 5) & 15;
  const int tid = threadIdx.x, lane = tid & 63, w = tid >> 6;
  const int fr = lane & 15, kg = lane >> 4;
  const int k8 = kg * 8;
  const int frl = fr & 3, frh = fr >> 2;

  __shared__ __align__(16) bf16 Klds[2][64*64];
  __shared__ __align__(16) bf16 Vlds[2][64*64];

  const long qrow = (long)qt*64 + w*16 + fr;
  const bf16* qbase = q + ((long)b*NS + qrow)*ND + h*NHD;
  bf16x8 qf[2];
  qf[0] = *(const bf16x8*)(qbase + k8);
  qf[1] = *(const bf16x8*)(qbase + 32 + k8);

  const bf16* kbase = k + (long)b*NS*ND + h*NHD;
  const bf16* vbase = v + (long)b*NS*ND + h*NHD;

  auto stageK = [&](int kt, int bufi) {
#pragma unroll
    for (int i = 0; i < 2; ++i) {
      int slot = i*256 + tid;
      int row = slot >> 3, c = slot & 7;
      int csrc = c ^ (row & 7) ^ (((row >> 3) & 1) << 2);
      async_copy16((char*)&Klds[bufi][0] + i*4096 + w*1024,
                   kbase + ((long)kt*64 + row)*ND + csrc*8);
    }
  };
  auto stageV = [&](int kt, int bufi) {
#pragma unroll
    for (int i = 0; i < 2; ++i) {
      int kr = i*32 + (tid >> 5)*4 + ((tid & 7) >> 1);
      int dc = ((tid >> 3) & 3)*16 + (tid & 1)*8;
      async_copy16((char*)&Vlds[bufi][0] + i*4096 + w*1024,
                   vbase + ((long)kt*64 + kr)*ND + dc);
    }
  };

  const f32x4 fzero = {0.f, 0.f, 0.f, 0.f};
  f32x4 oacc[4];
#pragma unroll
  for (int n = 0; n < 4; ++n) oacc[n] = fzero;
  float lsum = 0.f;
  const float* mbb = mbias + (long)b*NS;

  stageK(0, 0);
  stageV(0, 0);
  asm volatile("s_waitcnt vmcnt(0)" ::: "memory");
  __builtin_amdgcn_s_barrier();
  __builtin_amdgcn_sched_barrier(0);

  const int NT = NS / 64;
  for (int kt = 0; kt < NT; ++kt) {
    const int cur = kt & 1;
    if (kt + 1 < NT) { stageK(kt + 1, cur ^ 1); stageV(kt + 1, cur ^ 1); }
    const char* Kb = (const char*)&Klds[cur][0];
    const char* Vb = (const char*)&Vlds[cur][0];

    f32x4 sacc[4];
#pragma unroll
    for (int n = 0; n < 4; ++n) sacc[n] = fzero;
#pragma unroll
    for (int n = 0; n < 4; ++n) {
      int r = (frh << 3) + ((n & 1) << 2) + frl + ((n >> 1) << 5);
      int swzr = (r & 7) ^ (((r >> 3) & 1) << 2);
#pragma unroll
      for (int kk = 0; kk < 2; ++kk) {
        bf16x8 kf = *(const bf16x8*)(Kb + r*128 + ((((kk << 2) | kg) ^ swzr) << 4));
        sacc[n] = __builtin_amdgcn_mfma_f32_16x16x32_bf16(kf, qf[kk], sacc[n], 0, 0, 0);
      }
    }

    float p[4][4];
#pragma unroll
    for (int n = 0; n < 4; ++n) {
      float4 mb = *(const float4*)&mbb[kt*64 + kg*8 + ((n & 1) << 2) + ((n >> 1) << 5)];
      p[n][0] = exp2f(sacc[n][0] + mb.x);
      p[n][1] = exp2f(sacc[n][1] + mb.y);
      p[n][2] = exp2f(sacc[n][2] + mb.z);
      p[n][3] = exp2f(sacc[n][3] + mb.w);
    }
#pragma unroll
    for (int n = 0; n < 4; ++n)
      lsum += (p[n][0] + p[n][1]) + (p[n][2] + p[n][3]);

    bf16x8 paf[2];
#pragma unroll
    for (int n = 0; n < 4; ++n) {
#pragma unroll
      for (int j = 0; j < 4; ++j)
        paf[n >> 1][((n & 1) << 2) + j] = (bf16)p[n][j];
    }

#pragma unroll
    for (int kk = 0; kk < 2; ++kk) {
      bf16x4v t0[4], t1[4];
#pragma unroll
      for (int n2 = 0; n2 < 4; ++n2) {
        t0[n2] = tr_read16(Vb + (((kk*8 + 0)*4 + n2)*128 + kg*1024 + fr*8));
        t1[n2] = tr_read16(Vb + (((kk*8 + 1)*4 + n2)*128 + kg*1024 + fr*8));
      }
      asm volatile("s_waitcnt lgkmcnt(0)" ::: "memory");
      __builtin_amdgcn_sched_barrier(0);
#pragma unroll
      for (int n2 = 0; n2 < 4; ++n2) {
        bf16x8 vb8 = __builtin_shufflevector(t0[n2], t1[n2], 0, 1, 2, 3, 4, 5, 6, 7);
        oacc[n2] = __builtin_amdgcn_mfma_f32_16x16x32_bf16(paf[kk], vb8, oacc[n2], 0, 0, 0);
      }
    }

    asm volatile("s_waitcnt vmcnt(0)" ::: "memory");
    __builtin_amdgcn_s_barrier();
    __builtin_amdgcn_sched_barrier(0);
  }

  lsum += __shfl_xor(lsum, 16);
  lsum += __shfl_xor(lsum, 32);
#pragma unroll
  for (int j = 0; j < 4; ++j) {
    float lj = __shfl(lsum, kg*4 + j);
    float inv = 1.0f / lj;
    long orow = (long)qt*64 + w*16 + kg*4 + j;
    bf16* ob = out + ((long)b*NS + orow)*ND + h*NHD;
#pragma unroll
    for (int n2 = 0; n2 < 4; ++n2) ob[n2*16 + fr] = (bf16)(oacc[n2][j] * inv);
  }
}

// ---------------------------------------------------------------------------
extern "C" void kernel_launch(void* const* d_in, const int* in_sizes, int n_in,
                              void* d_out, int out_size, void* d_ws, size_t ws_size,
                              hipStream_t stream) {
  const float* x    = (const float*)d_in[0];
  const int*   mask = (const int*)d_in[1];
  const float* wq   = (const float*)d_in[2];
  const float* bq   = (const float*)d_in[3];
  const float* wk   = (const float*)d_in[4];
  const float* bk   = (const float*)d_in[5];
  const float* wv   = (const float*)d_in[6];
  const float* bv   = (const float*)d_in[7];
  const float* wo   = (const float*)d_in[8];
  const float* bo   = (const float*)d_in[9];
  const float* ln1w = (const float*)d_in[10];
  const float* ln1b = (const float*)d_in[11];
  const float* ln2w = (const float*)d_in[12];
  const float* ln2b = (const float*)d_in[13];
  const float* w1   = (const float*)d_in[14];
  const float* b1   = (const float*)d_in[15];
  const float* w2   = (const float*)d_in[16];
  const float* b2   = (const float*)d_in[17];
  float* out = (float*)d_out;

  char* ws = (char*)d_ws;
  const size_t MB = 1024ull * 1024ull;
  bf16* wqt = (bf16*)(ws + 0*MB);    // wq|wk|wv contiguous for fused QKV
  bf16* wkt = (bf16*)(ws + 2*MB);
  bf16* wvt = (bf16*)(ws + 4*MB);
  bf16* wot = (bf16*)(ws + 6*MB);
  bf16* w1t = (bf16*)(ws + 8*MB);    // 8MB
  bf16* w2t = (bf16*)(ws + 16*MB);   // 8MB
  bf16* h1   = (bf16*)(ws + 24*MB);
  bf16* qb   = (bf16*)(ws + 32*MB);  // q|k|v contiguous (8MB each)
  bf16* kb   = (bf16*)(ws + 40*MB);
  bf16* vb   = (bf16*)(ws + 48*MB);
  bf16* attn = h1;                   // alias: h1 dead after QKV
  bf16* f1   = (bf16*)(ws + 24*MB);  // alias h1/q/k/v (dead after out-proj)
  float* y1  = (float*)(ws + 56*MB); // 16MB
  bf16* h2   = (bf16*)(ws + 72*MB);  // 8MB
  float* bcat = (float*)(ws + 80*MB);          // 12KB
  float* mbf  = (float*)(ws + 80*MB + 12*1024);// 16KB (B*S floats)
  (void)in_sizes; (void)n_in; (void)out_size; (void)ws_size;

  transpose_all<<<12288, dim3(32, 8), 0, stream>>>(wq, wk, wv, wo, w1, w2,
                                                   wqt, wkt, wvt, wot, w1t, w2t);
  smallfuse_kernel<<<28, 256, 0, stream>>>(bq, bk, bv, bcat, mask, mbf);

  ln_kernel<<<NM, 256, 0, stream>>>(x, ln1w, ln1b, h1);

  // fused QKV (256^2): A=h1 (4096x1024), Bt=wqt|wkt|wvt (3072x1024)
  gemm256_kernel<3><<<dim3(12, 16), 512, 0, stream>>>(h1, wqt, bcat, qb,
                                                      NM, 3*ND, ND);
  rope_kernel<<<4096, 256, 0, stream>>>(qb, kb);
  attn_kernel<<<dim3(NS/64, NB*NH), 256, 0, stream>>>(qb, kb, vb, mbf, attn);

  // out-proj + residual(x) -> y1 (fp32)
  gemm_kernel<2><<<dim3(8, 32), 256, 0, stream>>>(attn, wot, bo, x, y1,
                                                  NM, ND, ND);
  ln_kernel<<<NM, 256, 0, stream>>>(y1, ln2w, ln2b, h2);
  // FFN1 + GELU (256^2) -> f1 (bf16)
  gemm256_kernel<1><<<dim3(16, 16), 512, 0, stream>>>(h2, w1t, b1, f1,
                                                      NM, NFF, ND);
  // FFN2 + residual(y1) -> out (fp32)
  gemm_kernel<2><<<dim3(8, 32), 256, 0, stream>>>(f1, w2t, b2, y1, out,
                                                  NM, ND, NFF);
}